// Round 1
// baseline (10657.298 us; speedup 1.0000x reference)
//
#include <hip/hip_runtime.h>
#include <hip/hip_bf16.h>

// ---------------------------------------------------------------------------
// 2-layer LSTM, B=64 T=256 N=512 H=1024.
// Phase 1: init/convert (f32 -> f16 weights, x transpose, bias fold, state).
// Phase 2: big MFMA GEMM  pre0[t*B+b][j] = x[b,t,:] @ W_ih0^T + b_ih0 + b_hh0.
// Phase 3: persistent pipelined kernel: per epoch e, layer0 computes step e
//          while layer1 computes step e-1; one grid barrier per epoch.
// ---------------------------------------------------------------------------

#define T_ 256
#define B_ 64
#define N_ 512
#define H_ 1024
#define FH_ 4096
#define NWG_SEQ 64

typedef _Float16 f16;
typedef _Float16 f16x8 __attribute__((ext_vector_type(8)));
typedef float f32x4 __attribute__((ext_vector_type(4)));

__device__ __forceinline__ float sigf(float x) { return 1.f / (1.f + __expf(-x)); }
__device__ __forceinline__ float tanhf_fast(float x) { return 1.f - 2.f / (__expf(2.f * x) + 1.f); }

// ---------------------------------------------------------------------------
// init / convert kernel
// ---------------------------------------------------------------------------
__global__ __launch_bounds__(256) void init_all(
    const float* __restrict__ x, const float* __restrict__ h, const float* __restrict__ cin,
    const float* __restrict__ Wih0, const float* __restrict__ bih0, const float* __restrict__ bhh0,
    const float* __restrict__ Whh0, const float* __restrict__ Wih1, const float* __restrict__ Whh1,
    const float* __restrict__ bih1, const float* __restrict__ bhh1,
    f16* __restrict__ xT, f16* __restrict__ wih0, f16* __restrict__ whh0,
    f16* __restrict__ wih1, f16* __restrict__ whh1,
    float* __restrict__ bias0, float* __restrict__ bias1,
    f16* __restrict__ hinit, float* __restrict__ c0, float* __restrict__ c1,
    unsigned* __restrict__ bar)
{
  const int stride = gridDim.x * blockDim.x;
  const int t0 = blockIdx.x * blockDim.x + threadIdx.x;

  // x[B,T,N] -> xT[(t*B+b), N] as f16
  for (int i = t0; i < T_ * B_ * N_; i += stride) {
    int n = i & (N_ - 1);
    int tb = i >> 9;           // / N_
    int b = tb & (B_ - 1);
    int t = tb >> 6;           // / B_
    xT[i] = (f16)x[((size_t)b * T_ + t) * N_ + n];
  }
  for (int i = t0; i < FH_ * N_; i += stride) wih0[i] = (f16)Wih0[i];
  for (int i = t0; i < FH_ * H_; i += stride) {
    whh0[i] = (f16)Whh0[i];
    wih1[i] = (f16)Wih1[i];
    whh1[i] = (f16)Whh1[i];
  }
  for (int i = t0; i < FH_; i += stride) {
    bias0[i] = bih0[i] + bhh0[i];
    bias1[i] = bih1[i] + bhh1[i];
  }
  for (int i = t0; i < 2 * B_ * H_; i += stride) hinit[i] = (f16)h[i];
  for (int i = t0; i < B_ * H_; i += stride) {
    c0[i] = cin[i];
    c1[i] = cin[B_ * H_ + i];
  }
  if (t0 < 8) bar[t0] = 0u;
}

// ---------------------------------------------------------------------------
// GEMM: pre0 = xT @ wih0^T + bias0, stored f16.  M=16384 N=4096 K=512.
// Block = 4 waves; wave w computes one 64x64 tile (global-direct fragments).
// Grid = (M/64) * (4096/64/4) = 256 * 16 = 4096 blocks.
// ---------------------------------------------------------------------------
__global__ __launch_bounds__(256) void gemm_pre0(
    const f16* __restrict__ xT, const f16* __restrict__ wih0,
    const float* __restrict__ bias0, f16* __restrict__ pre0)
{
  const int wid = threadIdx.x >> 6;
  const int lane = threadIdx.x & 63;
  const int lr = lane & 15;
  const int lkq = (lane >> 4) << 3;   // k offset of this lane group
  const int lrq = (lane >> 4) << 2;   // row offset within D frag

  const int mt = blockIdx.x & 255;          // row tile (64 rows)
  const int ct = (blockIdx.x >> 8) * 4 + wid; // col tile (64 cols)
  const int row0 = mt * 64, col0 = ct * 64;

  f32x4 acc[4][4] = {};
  const f16* Abase = xT + (size_t)row0 * N_;

  #pragma unroll 2
  for (int kk = 0; kk < N_ / 32; ++kk) {
    const int k = kk * 32 + lkq;
    f16x8 a[4], b[4];
    #pragma unroll
    for (int r = 0; r < 4; ++r)
      a[r] = *(const f16x8*)(Abase + (size_t)(r * 16 + lr) * N_ + k);
    #pragma unroll
    for (int cf = 0; cf < 4; ++cf)
      b[cf] = *(const f16x8*)(wih0 + (size_t)(col0 + cf * 16 + lr) * N_ + k);
    #pragma unroll
    for (int r = 0; r < 4; ++r)
      #pragma unroll
      for (int cf = 0; cf < 4; ++cf)
        acc[r][cf] = __builtin_amdgcn_mfma_f32_16x16x32_f16(a[r], b[cf], acc[r][cf], 0, 0, 0);
  }

  #pragma unroll
  for (int r = 0; r < 4; ++r) {
    #pragma unroll
    for (int cf = 0; cf < 4; ++cf) {
      const int col = col0 + cf * 16 + lr;
      const float bv = bias0[col];
      #pragma unroll
      for (int ri = 0; ri < 4; ++ri) {
        const int row = row0 + r * 16 + lrq + ri;
        pre0[(size_t)row * FH_ + col] = (f16)(acc[r][cf][ri] + bv);
      }
    }
  }
}

// ---------------------------------------------------------------------------
// Grid barrier (sense via monotonically increasing generation = epoch index).
// ---------------------------------------------------------------------------
__device__ __forceinline__ void grid_barrier(unsigned* cnt, unsigned* gen, unsigned idx)
{
  __syncthreads();
  if (threadIdx.x == 0) {
    __threadfence();  // release: publish this WG's h/c writes agent-wide
    unsigned a = __hip_atomic_fetch_add(cnt, 1u, __ATOMIC_ACQ_REL, __HIP_MEMORY_SCOPE_AGENT);
    if (a == NWG_SEQ - 1) {
      __hip_atomic_store(cnt, 0u, __ATOMIC_RELAXED, __HIP_MEMORY_SCOPE_AGENT);
      __hip_atomic_store(gen, idx + 1u, __ATOMIC_RELEASE, __HIP_MEMORY_SCOPE_AGENT);
    } else {
      while (__hip_atomic_load(gen, __ATOMIC_ACQUIRE, __HIP_MEMORY_SCOPE_AGENT) < idx + 1u)
        __builtin_amdgcn_s_sleep(2);
    }
    __threadfence();  // acquire: invalidate stale caches before next reads
  }
  __syncthreads();
}

// ---------------------------------------------------------------------------
// Pipelined sequential kernel. 64 WGs x 256 threads.
//   WG 0..31  : layer 0, h-slice ks = wg*32, active epochs [0, T)
//   WG 32..63 : layer 1, h-slice ks = (wg-32)*32, active epochs [1, T]
// Per WG: wave w computes gate w for all 64 batch rows x 32 slice cols.
// A (h vectors) staged in LDS (XOR-swizzled); B (weights) read global-direct.
// ---------------------------------------------------------------------------
__global__ __launch_bounds__(256) void lstm_seq(
    const f16* __restrict__ pre0, const f16* __restrict__ whh0,
    const f16* __restrict__ wih1, const f16* __restrict__ whh1,
    const float* __restrict__ bias1, const f16* __restrict__ hinit,
    f16* __restrict__ h0buf, f16* __restrict__ h1buf,
    float* __restrict__ c0, float* __restrict__ c1,
    float* __restrict__ out, unsigned* __restrict__ bar)
{
  __shared__ __align__(16) union {
    unsigned char a[B_ * H_ * 2];     // 128 KiB staged h tile (f16, swizzled)
    float g[4][B_][33];               // gate exchange (padded stride 33)
  } sm;

  const int tid = threadIdx.x;
  const int wid = tid >> 6;           // wave = gate index (i,f,g,o)
  const int lane = tid & 63;
  const int lr = lane & 15;
  const int lkq = (lane >> 4) << 3;
  const int lrq = (lane >> 4) << 2;

  const int wgid = blockIdx.x;
  const int layer = wgid >> 5;
  const int ks = (wgid & 31) * 32;

  float* cst = layer ? c1 : c0;
  float* out_h = out + (size_t)B_ * T_ * H_ + (size_t)layer * B_ * H_;
  float* out_c = out_h + 2 * B_ * H_;

  for (int e = 0; e <= T_; ++e) {
    const bool active = layer ? (e >= 1) : (e < T_);
    if (active) {
      const int t = layer ? (e - 1) : e;
      f32x4 acc[4][2] = {};
      float pv[4][2][4];

      // prefetch additive term: pre0 slice (layer0) or bias1 (layer1)
      if (layer == 0) {
        const f16* ps = pre0 + (size_t)t * B_ * FH_;
        #pragma unroll
        for (int cf = 0; cf < 2; ++cf) {
          const int col = wid * H_ + ks + cf * 16 + lr;
          #pragma unroll
          for (int r = 0; r < 4; ++r)
            #pragma unroll
            for (int ri = 0; ri < 4; ++ri)
              pv[r][cf][ri] = (float)ps[(size_t)(r * 16 + lrq + ri) * FH_ + col];
        }
      } else {
        #pragma unroll
        for (int cf = 0; cf < 2; ++cf) {
          const float bv = bias1[wid * H_ + ks + cf * 16 + lr];
          #pragma unroll
          for (int r = 0; r < 4; ++r)
            #pragma unroll
            for (int ri = 0; ri < 4; ++ri)
              pv[r][cf][ri] = bv;
        }
      }

      const int nchunk = layer ? 2 : 1;
      for (int cc = 0; cc < nchunk; ++cc) {
        const f16* hsrc;
        const f16* W;
        if (layer == 0) {
          hsrc = (e == 0) ? hinit : h0buf + (size_t)((e - 1) & 1) * (B_ * H_);
          W = whh0;
        } else if (cc == 0) {
          hsrc = h0buf + (size_t)((e - 1) & 1) * (B_ * H_);   // h0[t] from last epoch
          W = wih1;
        } else {
          hsrc = (e == 1) ? hinit + B_ * H_
                          : h1buf + (size_t)((e - 1) & 1) * (B_ * H_);
          W = whh1;
        }

        // stage 64x1024 f16 h tile into LDS with XOR swizzle (16B granules)
        #pragma unroll 4
        for (int it = 0; it < 32; ++it) {
          const int ch = tid + it * 256;          // 16B chunk id, 0..8191
          const int row = ch >> 7;                // 128 chunks per row
          f16x8 v = *(const f16x8*)(hsrc + ((size_t)ch << 3));
          const int dst = (ch << 4) ^ ((row & 7) << 4);
          *(f16x8*)(&sm.a[dst]) = v;
        }
        __syncthreads();

        // K loop: 32 steps of 16x16x32, 2 col frags, 4 row frags
        const f16* Wb = W + (size_t)(wid * H_ + ks + lr) * H_ + lkq;
        #pragma unroll 2
        for (int kk = 0; kk < 32; ++kk) {
          const int k = kk * 32 + lkq;
          f16x8 a[4], b[2];
          #pragma unroll
          for (int r = 0; r < 4; ++r) {
            const int row = r * 16 + lr;
            const int byt = (row * 2048 + k * 2) ^ ((row & 7) << 4);
            a[r] = *(const f16x8*)(&sm.a[byt]);
          }
          #pragma unroll
          for (int cf = 0; cf < 2; ++cf)
            b[cf] = *(const f16x8*)(Wb + (size_t)cf * 16 * H_ + kk * 32);
          #pragma unroll
          for (int r = 0; r < 4; ++r)
            #pragma unroll
            for (int cf = 0; cf < 2; ++cf)
              acc[r][cf] = __builtin_amdgcn_mfma_f32_16x16x32_f16(a[r], b[cf], acc[r][cf], 0, 0, 0);
        }
        __syncthreads();
      }

      // gate exchange via LDS (reuses A region; safe after syncthreads)
      #pragma unroll
      for (int r = 0; r < 4; ++r)
        #pragma unroll
        for (int cf = 0; cf < 2; ++cf)
          #pragma unroll
          for (int ri = 0; ri < 4; ++ri)
            sm.g[wid][r * 16 + lrq + ri][cf * 16 + lr] = acc[r][cf][ri] + pv[r][cf][ri];
      __syncthreads();

      // elementwise LSTM cell update for 64 rows x 32 cols
      f16* hb = (layer ? h1buf : h0buf) + (size_t)(e & 1) * (B_ * H_);
      #pragma unroll
      for (int ii = 0; ii < 8; ++ii) {
        const int cell = tid + ii * 256;
        const int row = cell >> 5, col = cell & 31;
        const float iv = sm.g[0][row][col];
        const float fv = sm.g[1][row][col];
        const float gv = sm.g[2][row][col];
        const float ov = sm.g[3][row][col];
        const int kg = ks + col;
        const size_t ci = (size_t)row * H_ + kg;
        const float cold = cst[ci];
        const float cn = sigf(fv) * cold + sigf(iv) * tanhf_fast(gv);
        const float hn = sigf(ov) * tanhf_fast(cn);
        cst[ci] = cn;
        hb[ci] = (f16)hn;
        out_h[ci] = hn;
        out_c[ci] = cn;
        if (layer) out[(size_t)row * (T_ * H_) + (size_t)t * H_ + kg] = hn;
      }
    }
    grid_barrier(bar, bar + 1, (unsigned)e);
  }
}

// ---------------------------------------------------------------------------
extern "C" void kernel_launch(void* const* d_in, const int* in_sizes, int n_in,
                              void* d_out, int out_size, void* d_ws, size_t ws_size,
                              hipStream_t stream)
{
  const float* x    = (const float*)d_in[0];
  const float* h    = (const float*)d_in[1];
  const float* c    = (const float*)d_in[2];
  const float* Wih0 = (const float*)d_in[3];
  const float* Whh0 = (const float*)d_in[4];
  const float* bih0 = (const float*)d_in[5];
  const float* bhh0 = (const float*)d_in[6];
  const float* Wih1 = (const float*)d_in[7];
  const float* Whh1 = (const float*)d_in[8];
  const float* bih1 = (const float*)d_in[9];
  const float* bhh1 = (const float*)d_in[10];

  char* w = (char*)d_ws;
  size_t off = 0;
  auto carve = [&](size_t bytes) -> char* {
    char* p = w + off;
    off = (off + bytes + 255) & ~(size_t)255;
    return p;
  };
  f16*   pre0  = (f16*)  carve((size_t)T_ * B_ * FH_ * 2);
  f16*   xT    = (f16*)  carve((size_t)T_ * B_ * N_ * 2);
  f16*   wih0  = (f16*)  carve((size_t)FH_ * N_ * 2);
  f16*   whh0  = (f16*)  carve((size_t)FH_ * H_ * 2);
  f16*   wih1  = (f16*)  carve((size_t)FH_ * H_ * 2);
  f16*   whh1  = (f16*)  carve((size_t)FH_ * H_ * 2);
  float* bias0 = (float*)carve((size_t)FH_ * 4);
  float* bias1 = (float*)carve((size_t)FH_ * 4);
  f16*   hinit = (f16*)  carve((size_t)2 * B_ * H_ * 2);
  f16*   h0buf = (f16*)  carve((size_t)2 * B_ * H_ * 2);
  f16*   h1buf = (f16*)  carve((size_t)2 * B_ * H_ * 2);
  float* c0    = (float*)carve((size_t)B_ * H_ * 4);
  float* c1    = (float*)carve((size_t)B_ * H_ * 4);
  unsigned* bar = (unsigned*)carve(256);
  if (off > ws_size) return;  // insufficient workspace -> fail loudly

  init_all<<<2048, 256, 0, stream>>>(x, h, c, Wih0, bih0, bhh0, Whh0, Wih1, Whh1, bih1, bhh1,
                                     xT, wih0, whh0, wih1, whh1, bias0, bias1, hinit, c0, c1, bar);
  gemm_pre0<<<4096, 256, 0, stream>>>(xT, wih0, bias0, pre0);
  lstm_seq<<<NWG_SEQ, 256, 0, stream>>>(pre0, whh0, wih1, whh1, bias1, hinit,
                                        h0buf, h1buf, c0, c1, (float*)d_out, bar);
}